// Round 1
// baseline (862.803 us; speedup 1.0000x reference)
//
#include <hip/hip_runtime.h>
#include <hip/hip_bf16.h>
#include <cstdint>
#include <cstddef>

#define S_LEN 2048
#define HID   4096
#define NHEADS 32
#define NKVH   8
#define HDIM   128

using bf16x8 = __attribute__((ext_vector_type(8))) short;
using f32x4  = __attribute__((ext_vector_type(4))) float;

__device__ __forceinline__ short f2bf(float f) {
  union { float f; unsigned u; } a; a.f = f;
  unsigned u = a.u;
  unsigned r = u + 0x7fffu + ((u >> 16) & 1u);   // RNE
  return (short)(r >> 16);
}
__device__ __forceinline__ float bf2f(short v) {
  union { unsigned u; float f; } a;
  a.u = ((unsigned)(unsigned short)v) << 16;
  return a.f;
}

// async 16B global -> LDS (wave-uniform base + lane*16 on HW)
__device__ __forceinline__ void gld16(const void* g, void* l) {
  __builtin_amdgcn_global_load_lds((__attribute__((address_space(1))) void*)(void*)g,
                                   (__attribute__((address_space(3))) void*)l, 16, 0, 0);
}

// ---------------- fp32 -> bf16 elementwise (x4 vectorized) ----------------
__global__ void cvt_f32_bf16(const float* __restrict__ x, short* __restrict__ y, int n4) {
  int i = blockIdx.x * blockDim.x + threadIdx.x;
  if (i >= n4) return;
  float4 v = reinterpret_cast<const float4*>(x)[i];
  short4 o;
  o.x = f2bf(v.x); o.y = f2bf(v.y); o.z = f2bf(v.z); o.w = f2bf(v.w);
  reinterpret_cast<short4*>(y)[i] = o;
}

// ------------- transpose + convert: W[K][N] fp32 -> Wt[N][K] bf16 -------------
__global__ void transpose_to_bf16(const float* __restrict__ W, short* __restrict__ Wt,
                                  int K, int N) {
  __shared__ float tile[32][33];
  int bn = blockIdx.x * 32;
  int bk = blockIdx.y * 32;
  int tx = threadIdx.x & 31;
  int ty = (threadIdx.x >> 5) * 4;   // 256 threads: 8 groups x 4 rows
#pragma unroll
  for (int i = 0; i < 4; ++i)
    tile[ty + i][tx] = W[(size_t)(bk + ty + i) * N + bn + tx];
  __syncthreads();
#pragma unroll
  for (int i = 0; i < 4; ++i)
    Wt[(size_t)(bn + ty + i) * K + bk + tx] = f2bf(tile[tx][ty + i]);
}

// ---------------- bf16 GEMM: C[M][N] = A[M][K] * Bt[N][K]^T ----------------
// EPI 0: bf16 row-major C; 1: bf16 transposed (C^T, ld=ldt); 2: fp32 row-major C
template <int EPI>
__global__ __launch_bounds__(256)
void gemm_bt(const short* __restrict__ A, const short* __restrict__ B,
             void* __restrict__ Cp, int M, int N, int K, int ldt) {
  __shared__ short As[128 * 32];
  __shared__ short Bs[128 * 32];
  const int bn = blockIdx.x * 128;
  const int bm = blockIdx.y * 128;
  const int t = threadIdx.x;
  const int lane = t & 63;
  const int wave = t >> 6;
  const int wm = (wave >> 1) * 64;
  const int wn = (wave & 1) * 64;
  const int lr = lane & 15;
  const int lk = (lane >> 4) * 8;

  f32x4 acc[4][4] = {};

  const int arow = t >> 2;           // 0..63
  const int acol = (t & 3) * 8;
  const size_t ab0 = (size_t)(bm + arow) * K + acol;
  const size_t ab1 = (size_t)(bm + 64 + arow) * K + acol;
  const size_t bb0 = (size_t)(bn + arow) * K + acol;
  const size_t bb1 = (size_t)(bn + 64 + arow) * K + acol;
  char* asl0 = (char*)As + t * 16;
  char* asl1 = (char*)As + 4096 + t * 16;
  char* bsl0 = (char*)Bs + t * 16;
  char* bsl1 = (char*)Bs + 4096 + t * 16;

  for (int k0 = 0; k0 < K; k0 += 32) {
    __syncthreads();
    gld16(A + ab0 + k0, asl0);
    gld16(A + ab1 + k0, asl1);
    gld16(B + bb0 + k0, bsl0);
    gld16(B + bb1 + k0, bsl1);
    __syncthreads();
    bf16x8 af[4], bfr[4];
#pragma unroll
    for (int i = 0; i < 4; ++i)
      af[i] = *(const bf16x8*)&As[(wm + i * 16 + lr) * 32 + lk];
#pragma unroll
    for (int j = 0; j < 4; ++j)
      bfr[j] = *(const bf16x8*)&Bs[(wn + j * 16 + lr) * 32 + lk];
#pragma unroll
    for (int i = 0; i < 4; ++i)
#pragma unroll
      for (int j = 0; j < 4; ++j)
        acc[i][j] = __builtin_amdgcn_mfma_f32_16x16x32_bf16(af[i], bfr[j], acc[i][j], 0, 0, 0);
  }

  const int cr = (lane >> 4) << 2;   // C/D: row=(lane>>4)*4+reg, col=lane&15
  const int cc = lane & 15;
#pragma unroll
  for (int i = 0; i < 4; ++i) {
#pragma unroll
    for (int j = 0; j < 4; ++j) {
      int row = bm + wm + i * 16 + cr;
      int col = bn + wn + j * 16 + cc;
#pragma unroll
      for (int r = 0; r < 4; ++r) {
        if (EPI == 0)      ((short*)Cp)[(size_t)(row + r) * N + col] = f2bf(acc[i][j][r]);
        else if (EPI == 1) ((short*)Cp)[(size_t)col * ldt + row + r] = f2bf(acc[i][j][r]);
        else               ((float*)Cp)[(size_t)(row + r) * N + col] = acc[i][j][r];
      }
    }
  }
}

// ---------------- RoPE in-place on bf16 [S][nh*128], dims 0..63 ----------------
__global__ void rope_kernel(short* __restrict__ X, const float* __restrict__ cosb,
                            const float* __restrict__ sinb, int nh, int total) {
  int idx = blockIdx.x * blockDim.x + threadIdx.x;
  if (idx >= total) return;
  int j = idx & 31;
  int h = (idx >> 5) % nh;
  int s = idx / (nh * 32);
  float c = cosb[s * 64 + j];
  float sn = sinb[s * 64 + j];
  short* p = X + (size_t)s * (nh * HDIM) + h * HDIM + j;
  float x1 = bf2f(p[0]);
  float x2 = bf2f(p[32]);
  p[0]  = f2bf(x1 * c - x2 * sn);
  p[32] = f2bf(x2 * c + x1 * sn);
}

// ---------------- flash attention w/ sinks ----------------
// grid (16 qtiles, 32 heads), 512 threads (8 waves). BM=128, BN=64.
// Q: [S][4096] bf16 (post-RoPE), K: [S][1024] bf16 (post-RoPE), Vt: [1024][S] bf16
__global__ __launch_bounds__(512)
void attn_kernel(const short* __restrict__ Q, const short* __restrict__ Kb,
                 const short* __restrict__ Vt, const float* __restrict__ sinks,
                 short* __restrict__ O) {
  __shared__ short lds[24576];            // 48KB: Ks 64x128 | Vs 128x64 | Ps 128x64
  short* Ksp = lds;
  short* Vsp = lds + 64 * 128;
  short* Psp = lds + 64 * 128 + 128 * 64;

  const int qt = gridDim.x - 1 - blockIdx.x;   // heavy tiles first
  const int q0 = qt * 128;
  const int h = blockIdx.y;
  const int kvh = h >> 2;
  const int t = threadIdx.x;
  const int lane = t & 63;
  const int w = t >> 6;                   // wave 0..7 -> rows w*16..w*16+16
  const int lr = lane & 15;
  const int lq = lane >> 4;
  const int lk = lq * 8;

  // stage Q tile (128 x 128 bf16 = 32KB) into lds[0..16384)
#pragma unroll
  for (int c = 0; c < 4; ++c) {
    const short* g = Q + (size_t)(q0 + c * 32 + (t >> 4)) * (NHEADS * HDIM)
                       + h * HDIM + (t & 15) * 8;
    gld16(g, (char*)lds + c * 8192 + t * 16);
  }
  __syncthreads();
  bf16x8 qf[4];
#pragma unroll
  for (int s = 0; s < 4; ++s)
    qf[s] = *(const bf16x8*)&lds[(w * 16 + lr) * 128 + s * 32 + lk];
  __syncthreads();   // all Q-frag reads done before K/V staging overwrites

  f32x4 oa[8] = {};
  float mr[4], lsum[4];
#pragma unroll
  for (int r = 0; r < 4; ++r) { mr[r] = -INFINITY; lsum[r] = 0.f; }

  const int nkt = 2 * qt + 2;
  const float scale = 0.08838834764831845f;  // 1/sqrt(128)

  for (int kt = 0; kt < nkt; ++kt) {
    __syncthreads();
    // stage K tile: Ks[n][d], 64 rows x 256B
#pragma unroll
    for (int c = 0; c < 2; ++c) {
      const short* g = Kb + (size_t)(kt * 64 + c * 32 + (t >> 4)) * (NKVH * HDIM)
                          + kvh * HDIM + (t & 15) * 8;
      gld16(g, (char*)Ksp + c * 8192 + t * 16);
    }
    // stage V^T tile: Vs[d][kk], 128 rows x 128B
#pragma unroll
    for (int c = 0; c < 2; ++c) {
      const short* g = Vt + (size_t)(kvh * HDIM + c * 64 + (t >> 3)) * S_LEN
                          + kt * 64 + (t & 7) * 8;
      gld16(g, (char*)Vsp + c * 8192 + t * 16);
    }
    __syncthreads();

    // S = Q K^T : 4 n-tiles of 16
    f32x4 sa[4] = {};
#pragma unroll
    for (int s = 0; s < 4; ++s) {
#pragma unroll
      for (int j = 0; j < 4; ++j) {
        bf16x8 bk = *(const bf16x8*)&Ksp[(j * 16 + lr) * 128 + s * 32 + lk];
        sa[j] = __builtin_amdgcn_mfma_f32_16x16x32_bf16(qf[s], bk, sa[j], 0, 0, 0);
      }
    }

    // scale + causal mask + row max
    const int rbase = q0 + w * 16 + (lq << 2);
    float tm[4] = {-INFINITY, -INFINITY, -INFINITY, -INFINITY};
#pragma unroll
    for (int j = 0; j < 4; ++j) {
      int cg = kt * 64 + j * 16 + lr;
#pragma unroll
      for (int r = 0; r < 4; ++r) {
        float v = sa[j][r] * scale;
        v = (cg <= rbase + r) ? v : -INFINITY;
        sa[j][r] = v;
        tm[r] = fmaxf(tm[r], v);
      }
    }
#pragma unroll
    for (int off = 1; off < 16; off <<= 1)
#pragma unroll
      for (int r = 0; r < 4; ++r)
        tm[r] = fmaxf(tm[r], __shfl_xor(tm[r], off));

    float alpha[4];
#pragma unroll
    for (int r = 0; r < 4; ++r) {
      float mn = fmaxf(mr[r], tm[r]);
      alpha[r] = __expf(mr[r] - mn);
      mr[r] = mn;
    }
    float rs[4] = {0.f, 0.f, 0.f, 0.f};
#pragma unroll
    for (int j = 0; j < 4; ++j)
#pragma unroll
      for (int r = 0; r < 4; ++r) {
        float p = __expf(sa[j][r] - mr[r]);
        sa[j][r] = p;
        rs[r] += p;
      }
#pragma unroll
    for (int off = 1; off < 16; off <<= 1)
#pragma unroll
      for (int r = 0; r < 4; ++r)
        rs[r] += __shfl_xor(rs[r], off);
#pragma unroll
    for (int r = 0; r < 4; ++r)
      lsum[r] = lsum[r] * alpha[r] + rs[r];
#pragma unroll
    for (int j = 0; j < 8; ++j)
#pragma unroll
      for (int r = 0; r < 4; ++r)
        oa[j][r] *= alpha[r];

    // P (C-layout) -> LDS (A-layout source); wave-private rows, no barrier needed
#pragma unroll
    for (int j = 0; j < 4; ++j)
#pragma unroll
      for (int r = 0; r < 4; ++r)
        Psp[(w * 16 + (lq << 2) + r) * 64 + j * 16 + lr] = f2bf(sa[j][r]);

    // O += P V
#pragma unroll
    for (int kk = 0; kk < 2; ++kk) {
      bf16x8 pa = *(const bf16x8*)&Psp[(w * 16 + lr) * 64 + kk * 32 + lk];
#pragma unroll
      for (int j = 0; j < 8; ++j) {
        bf16x8 bv = *(const bf16x8*)&Vsp[(j * 16 + lr) * 64 + kk * 32 + lk];
        oa[j] = __builtin_amdgcn_mfma_f32_16x16x32_bf16(pa, bv, oa[j], 0, 0, 0);
      }
    }
  }

  // sink joins the softmax denominator only
  float snk = sinks[h];
#pragma unroll
  for (int r = 0; r < 4; ++r)
    lsum[r] += __expf(snk - mr[r]);

#pragma unroll
  for (int j = 0; j < 8; ++j)
#pragma unroll
    for (int r = 0; r < 4; ++r) {
      size_t row = q0 + w * 16 + (lq << 2) + r;
      O[row * (NHEADS * HDIM) + h * HDIM + j * 16 + lr] = f2bf(oa[j][r] / lsum[r]);
    }
}

// ---------------- host ----------------
extern "C" void kernel_launch(void* const* d_in, const int* in_sizes, int n_in,
                              void* d_out, int out_size, void* d_ws, size_t ws_size,
                              hipStream_t stream) {
  const float* hs    = (const float*)d_in[0];
  const float* cosb  = (const float*)d_in[1];
  const float* sinb  = (const float*)d_in[2];
  const float* Wq    = (const float*)d_in[4];
  const float* Wk    = (const float*)d_in[5];
  const float* Wv    = (const float*)d_in[6];
  const float* Wo    = (const float*)d_in[7];
  const float* sinks = (const float*)d_in[8];
  float* out = (float*)d_out;

  char* ws = (char*)d_ws;
  short* Xb  = (short*)(ws);                    // 16.8MB  [2048][4096]
  short* Wqt = (short*)(ws + 16777216);         // 33.6MB  [4096][4096] (later Wot)
  short* Wkt = (short*)(ws + 50331648);         //  8.4MB  [1024][4096]
  short* Wvt = (short*)(ws + 58720256);         //  8.4MB  [1024][4096]
  short* Qb  = (short*)(ws + 67108864);         // 16.8MB  [2048][4096]
  short* Kb  = (short*)(ws + 83886080);         //  4.2MB  [2048][1024]
  short* Vtb = (short*)(ws + 88080384);         //  4.2MB  [1024][2048]
  short* Ab  = Xb;                              // alias: X dead after V GEMM
  short* Wot = Wqt;                             // alias: Wqt dead after Q GEMM

  cvt_f32_bf16<<<8192, 256, 0, stream>>>(hs, Xb, 2097152);
  transpose_to_bf16<<<dim3(128, 128), 256, 0, stream>>>(Wq, Wqt, 4096, 4096);
  transpose_to_bf16<<<dim3(32, 128), 256, 0, stream>>>(Wk, Wkt, 4096, 1024);
  transpose_to_bf16<<<dim3(32, 128), 256, 0, stream>>>(Wv, Wvt, 4096, 1024);

  gemm_bt<0><<<dim3(32, 16), 256, 0, stream>>>(Xb, Wqt, Qb, 2048, 4096, 4096, 0);
  gemm_bt<0><<<dim3(8, 16), 256, 0, stream>>>(Xb, Wkt, Kb, 2048, 1024, 4096, 0);
  gemm_bt<1><<<dim3(8, 16), 256, 0, stream>>>(Xb, Wvt, Vtb, 2048, 1024, 4096, 2048);

  rope_kernel<<<8192, 256, 0, stream>>>(Qb, cosb, sinb, NHEADS, 2048 * NHEADS * 32);
  rope_kernel<<<2048, 256, 0, stream>>>(Kb, cosb, sinb, NKVH, 2048 * NKVH * 32);

  transpose_to_bf16<<<dim3(128, 128), 256, 0, stream>>>(Wo, Wot, 4096, 4096);

  attn_kernel<<<dim3(16, 32), 512, 0, stream>>>(Qb, Kb, Vtb, sinks, Ab);

  gemm_bt<2><<<dim3(32, 16), 256, 0, stream>>>(Ab, Wot, out, 2048, 4096, 4096, 0);
}

// Round 2
// 579.256 us; speedup vs baseline: 1.4895x; 1.4895x over previous
//
#include <hip/hip_runtime.h>
#include <hip/hip_bf16.h>
#include <cstdint>
#include <cstddef>

#define S_LEN 2048
#define NHEADS 32
#define NKVH   8
#define HDIM   128

using bf16x8 = __attribute__((ext_vector_type(8))) short;
using f32x4  = __attribute__((ext_vector_type(4))) float;
using f32x16 = __attribute__((ext_vector_type(16))) float;

__device__ __forceinline__ short f2bf(float f) {
  union { float f; unsigned u; } a; a.f = f;
  unsigned u = a.u;
  unsigned r = u + 0x7fffu + ((u >> 16) & 1u);   // RNE
  return (short)(r >> 16);
}
__device__ __forceinline__ unsigned pack_bf2(float lo, float hi) {
  union { float f; unsigned u; } a, b; a.f = lo; b.f = hi;
  // dst = [hi16(lo) | hi16(hi)<<16]  (truncation; consistent num/denom)
  return __builtin_amdgcn_perm(b.u, a.u, 0x07060302);
}

// async 16B global -> LDS (wave-uniform base + lane*16 on HW)
__device__ __forceinline__ void gld16(const void* g, void* l) {
  __builtin_amdgcn_global_load_lds((__attribute__((address_space(1))) void*)(void*)g,
                                   (__attribute__((address_space(3))) void*)l, 16, 0, 0);
}

// ---------------- fp32 -> bf16 elementwise (x4 vectorized) ----------------
__global__ void cvt_f32_bf16(const float* __restrict__ x, short* __restrict__ y, int n4) {
  int i = blockIdx.x * blockDim.x + threadIdx.x;
  if (i >= n4) return;
  float4 v = reinterpret_cast<const float4*>(x)[i];
  short4 o;
  o.x = f2bf(v.x); o.y = f2bf(v.y); o.z = f2bf(v.z); o.w = f2bf(v.w);
  reinterpret_cast<short4*>(y)[i] = o;
}

// ------------- transpose + convert: W[K][N] fp32 -> Wt[N][K] bf16 -------------
__global__ void transpose_to_bf16(const float* __restrict__ W, short* __restrict__ Wt,
                                  int K, int N) {
  __shared__ float tile[32][33];
  int bn = blockIdx.x * 32;
  int bk = blockIdx.y * 32;
  int tx = threadIdx.x & 31;
  int ty = (threadIdx.x >> 5) * 4;
#pragma unroll
  for (int i = 0; i < 4; ++i)
    tile[ty + i][tx] = W[(size_t)(bk + ty + i) * N + bn + tx];
  __syncthreads();
#pragma unroll
  for (int i = 0; i < 4; ++i)
    Wt[(size_t)(bn + ty + i) * K + bk + tx] = f2bf(tile[tx][ty + i]);
}

// ---------------- fused QKV GEMM + RoPE epilogue ----------------
// A: X [2048][4096] bf16. B: Wqkvt [6144][4096] bf16 (rows 0..4095 Q,
// 4096..5119 K, 5120..6143 V). Outputs: Qb [2048][4096] (roped),
// Kb [2048][1024] (roped), Vtb [1024][2048] (transposed).
__global__ __launch_bounds__(256)
void gemm_qkv(const short* __restrict__ A, const short* __restrict__ B,
              short* __restrict__ Qb, short* __restrict__ Kb, short* __restrict__ Vtb,
              const float* __restrict__ cosb, const float* __restrict__ sinb) {
  const int K = 4096;
  __shared__ short As[128 * 32];
  __shared__ short Bs[128 * 32];
  const int bn = blockIdx.x * 128;
  const int bm = blockIdx.y * 128;
  const int t = threadIdx.x;
  const int lane = t & 63;
  const int wave = t >> 6;
  const int wm = (wave >> 1) * 64;
  const int wn = (wave & 1) * 64;
  const int lr = lane & 15;
  const int lk = (lane >> 4) * 8;

  f32x4 acc[4][4] = {};

  const int arow = t >> 2;
  const int acol = (t & 3) * 8;
  const size_t ab0 = (size_t)(bm + arow) * K + acol;
  const size_t ab1 = (size_t)(bm + 64 + arow) * K + acol;
  const size_t bb0 = (size_t)(bn + arow) * K + acol;
  const size_t bb1 = (size_t)(bn + 64 + arow) * K + acol;
  char* asl0 = (char*)As + t * 16;
  char* asl1 = (char*)As + 4096 + t * 16;
  char* bsl0 = (char*)Bs + t * 16;
  char* bsl1 = (char*)Bs + 4096 + t * 16;

  for (int k0 = 0; k0 < K; k0 += 32) {
    __syncthreads();
    gld16(A + ab0 + k0, asl0);
    gld16(A + ab1 + k0, asl1);
    gld16(B + bb0 + k0, bsl0);
    gld16(B + bb1 + k0, bsl1);
    __syncthreads();
    bf16x8 af[4], bfr[4];
#pragma unroll
    for (int i = 0; i < 4; ++i)
      af[i] = *(const bf16x8*)&As[(wm + i * 16 + lr) * 32 + lk];
#pragma unroll
    for (int j = 0; j < 4; ++j)
      bfr[j] = *(const bf16x8*)&Bs[(wn + j * 16 + lr) * 32 + lk];
#pragma unroll
    for (int i = 0; i < 4; ++i)
#pragma unroll
      for (int j = 0; j < 4; ++j)
        acc[i][j] = __builtin_amdgcn_mfma_f32_16x16x32_bf16(af[i], bfr[j], acc[i][j], 0, 0, 0);
  }

  const int cr = (lane >> 4) << 2;
  const int cc = lane & 15;
  const int region = (bn >= 5120) ? 2 : (bn >= 4096 ? 1 : 0);

  // RoPE: cols (c, c+32) for c<32 within each 128-head-block live in
  // acc[i][0..1] vs acc[i][2..3] of the wn==0 wave.
  if (region < 2 && wn == 0) {
#pragma unroll
    for (int i = 0; i < 4; ++i) {
#pragma unroll
      for (int r = 0; r < 4; ++r) {
        int srow = bm + wm + i * 16 + cr + r;
#pragma unroll
        for (int j = 0; j < 2; ++j) {
          int c = j * 16 + cc;
          float cv = cosb[srow * 64 + c];
          float sv = sinb[srow * 64 + c];
          float x1 = acc[i][j][r], x2 = acc[i][j + 2][r];
          acc[i][j][r]     = x1 * cv - x2 * sv;
          acc[i][j + 2][r] = x2 * cv + x1 * sv;
        }
      }
    }
  }

#pragma unroll
  for (int i = 0; i < 4; ++i) {
#pragma unroll
    for (int j = 0; j < 4; ++j) {
      int row = bm + wm + i * 16 + cr;
      int col = bn + wn + j * 16 + cc;
#pragma unroll
      for (int r = 0; r < 4; ++r) {
        short v = f2bf(acc[i][j][r]);
        if (region == 0)      Qb[(size_t)(row + r) * 4096 + col] = v;
        else if (region == 1) Kb[(size_t)(row + r) * 1024 + (col - 4096)] = v;
        else                  Vtb[(size_t)(col - 5120) * 2048 + row + r] = v;
      }
    }
  }
}

// ---------------- output GEMM: out[M][N] fp32 = A * Bt^T ----------------
__global__ __launch_bounds__(256)
void gemm_out(const short* __restrict__ A, const short* __restrict__ B,
              float* __restrict__ C) {
  const int K = 4096, N = 4096;
  __shared__ short As[128 * 32];
  __shared__ short Bs[128 * 32];
  const int bn = blockIdx.x * 128;
  const int bm = blockIdx.y * 128;
  const int t = threadIdx.x;
  const int lane = t & 63;
  const int wave = t >> 6;
  const int wm = (wave >> 1) * 64;
  const int wn = (wave & 1) * 64;
  const int lr = lane & 15;
  const int lk = (lane >> 4) * 8;

  f32x4 acc[4][4] = {};

  const int arow = t >> 2;
  const int acol = (t & 3) * 8;
  const size_t ab0 = (size_t)(bm + arow) * K + acol;
  const size_t ab1 = (size_t)(bm + 64 + arow) * K + acol;
  const size_t bb0 = (size_t)(bn + arow) * K + acol;
  const size_t bb1 = (size_t)(bn + 64 + arow) * K + acol;
  char* asl0 = (char*)As + t * 16;
  char* asl1 = (char*)As + 4096 + t * 16;
  char* bsl0 = (char*)Bs + t * 16;
  char* bsl1 = (char*)Bs + 4096 + t * 16;

  for (int k0 = 0; k0 < K; k0 += 32) {
    __syncthreads();
    gld16(A + ab0 + k0, asl0);
    gld16(A + ab1 + k0, asl1);
    gld16(B + bb0 + k0, bsl0);
    gld16(B + bb1 + k0, bsl1);
    __syncthreads();
    bf16x8 af[4], bfr[4];
#pragma unroll
    for (int i = 0; i < 4; ++i)
      af[i] = *(const bf16x8*)&As[(wm + i * 16 + lr) * 32 + lk];
#pragma unroll
    for (int j = 0; j < 4; ++j)
      bfr[j] = *(const bf16x8*)&Bs[(wn + j * 16 + lr) * 32 + lk];
#pragma unroll
    for (int i = 0; i < 4; ++i)
#pragma unroll
      for (int j = 0; j < 4; ++j)
        acc[i][j] = __builtin_amdgcn_mfma_f32_16x16x32_bf16(af[i], bfr[j], acc[i][j], 0, 0, 0);
  }

  const int cr = (lane >> 4) << 2;
  const int cc = lane & 15;
#pragma unroll
  for (int i = 0; i < 4; ++i)
#pragma unroll
    for (int j = 0; j < 4; ++j) {
      int row = bm + wm + i * 16 + cr;
      int col = bn + wn + j * 16 + cc;
#pragma unroll
      for (int r = 0; r < 4; ++r)
        C[(size_t)(row + r) * N + col] = acc[i][j][r];
    }
}

// ---------------- flash attention, S^T form, max-free softmax ----------------
// grid (32 heads, 16 qtiles), 256 threads (4 waves). BM=128 (32 q-rows/wave),
// BN=64. 32x32x16 MFMA. Double-buffered K/V staging, XOR-swizzled LDS.
__global__ __launch_bounds__(256, 2)
void attn_kernel(const short* __restrict__ Q, const short* __restrict__ Kg,
                 const short* __restrict__ Vg, const float* __restrict__ sinks,
                 short* __restrict__ O) {
  __shared__ short lds[32768];   // 64 KB: buf0 [Ks 8192 | Vs 8192], buf1 same
  const int h = blockIdx.x;
  const int qt = 15 - blockIdx.y;          // heavy tiles first
  const int q0 = qt * 128;
  const int kvh = h >> 2;
  const int t = threadIdx.x;
  const int lane = t & 63;
  const int w = t >> 6;
  const int l31 = lane & 31;
  const int l7 = lane & 7;
  const bool qh = lane >= 32;
  const int q5 = qh ? 1 : 0;
  const int nkt = 2 * qt + 2;

  // --- staging address precompute (global col permuted so LDS is swizzled:
  //     data chunk ch lives at position ch ^ (row&7)) ---
  const int kch = (t & 15) ^ ((t >> 4) & 7);
  const short* kgb = Kg + (size_t)(t >> 4) * 1024 + kvh * 128 + kch * 8;
  const int vch = (t & 7) ^ ((t >> 3) & 7);
  const short* vgb = Vg + (size_t)(kvh * 128 + (t >> 3)) * 2048 + vch * 8;

  auto stage = [&](int kt, int b) {
    short* kl = lds + b * 16384 + t * 8;
    short* vl = lds + b * 16384 + 8192 + t * 8;
    const short* kg = kgb + (size_t)kt * 64 * 1024;
    const short* vg = vgb + kt * 64;
#pragma unroll
    for (int c = 0; c < 4; ++c) {
      gld16(kg + (size_t)c * 16 * 1024, kl + c * 2048);
      gld16(vg + (size_t)c * 32 * 2048, vl + c * 2048);
    }
  };

  // --- Q B-fragments straight from global (once) ---
  const short* qp = Q + (size_t)(q0 + w * 32 + l31) * 4096 + h * 128 + q5 * 8;
  bf16x8 qf[8];
#pragma unroll
  for (int st = 0; st < 8; ++st) qf[st] = *(const bf16x8*)(qp + st * 16);

  union { short s[8]; bf16x8 v; } ones;
#pragma unroll
  for (int i = 0; i < 8; ++i) ones.s[i] = (short)0x3F80;   // bf16 1.0

  f32x16 acc[4] = {};   // O^T: rows d (4 tiles of 32), col q = lane&31
  f32x16 lacc = {};     // ones^T * P: every reg = colsum(q) = softmax denom

  stage(0, 0);
  const int qg = q0 + w * 32 + l31;            // this lane's q (column) index
  const float ce = 0.12751743f;                // (1/sqrt(128)) * log2(e)

  for (int kt = 0; kt < nkt; ++kt) {
    const int b = kt & 1;
    __syncthreads();                            // staging of kt complete
    if (kt + 1 < nkt) stage(kt + 1, b ^ 1);     // prefetch hidden under compute
    const short* Ks = lds + b * 16384;
    const short* Vs = Ks + 8192;

    // S^T = K * Q^T  (two 32-row k-tiles)
    f32x16 sa0 = {}, sa1 = {};
#pragma unroll
    for (int st = 0; st < 8; ++st) {
      const int cp = ((st * 2 + q5) ^ l7) * 8;
      bf16x8 k0 = *(const bf16x8*)(Ks + (l31) * 128 + cp);
      bf16x8 k1 = *(const bf16x8*)(Ks + (32 + l31) * 128 + cp);
      sa0 = __builtin_amdgcn_mfma_f32_32x32x16_bf16(k0, qf[st], sa0, 0, 0, 0);
      sa1 = __builtin_amdgcn_mfma_f32_32x32x16_bf16(k1, qf[st], sa1, 0, 0, 0);
    }

    // exp2 (max-free); mask only on the two diagonal tiles
    if (kt >= 2 * qt) {
      const int kb0 = kt * 64 + q5 * 4;
#pragma unroll
      for (int r = 0; r < 16; ++r) {
        int kg0 = kb0 + ((r >> 2) << 3) + (r & 3);
        float s0 = (kg0 <= qg) ? sa0[r] * ce : -INFINITY;
        float s1 = (kg0 + 32 <= qg) ? sa1[r] * ce : -INFINITY;
        sa0[r] = __builtin_amdgcn_exp2f(s0);
        sa1[r] = __builtin_amdgcn_exp2f(s1);
      }
    } else {
#pragma unroll
      for (int r = 0; r < 16; ++r) {
        sa0[r] = __builtin_amdgcn_exp2f(sa0[r] * ce);
        sa1[r] = __builtin_amdgcn_exp2f(sa1[r] * ce);
      }
    }

    // P^T B-fragments via half-wave exchange; colsum MFMA; PV
#pragma unroll
    for (int s = 0; s < 4; ++s) {
      const f32x16& S = (s & 2) ? sa1 : sa0;
      float a0, a1, a2, a3, b0, b1, b2, b3;
      if (s & 1) {
        a0 = qh ? S[12] : S[8];  a1 = qh ? S[13] : S[9];
        a2 = qh ? S[14] : S[10]; a3 = qh ? S[15] : S[11];
        b0 = qh ? S[8]  : S[12]; b1 = qh ? S[9]  : S[13];
        b2 = qh ? S[10] : S[14]; b3 = qh ? S[11] : S[15];
      } else {
        a0 = qh ? S[4] : S[0]; a1 = qh ? S[5] : S[1];
        a2 = qh ? S[6] : S[2]; a3 = qh ? S[7] : S[3];
        b0 = qh ? S[0] : S[4]; b1 = qh ? S[1] : S[5];
        b2 = qh ? S[2] : S[6]; b3 = qh ? S[3] : S[7];
      }
      unsigned d0 = pack_bf2(a0, a1), d1 = pack_bf2(a2, a3);
      unsigned e0 = pack_bf2(b0, b1), e1 = pack_bf2(b2, b3);
      unsigned r0 = (unsigned)__shfl_xor((int)e0, 32, 64);
      unsigned r1 = (unsigned)__shfl_xor((int)e1, 32, 64);
      union { unsigned u[4]; bf16x8 v; } P;
      P.u[0] = qh ? r0 : d0;  P.u[1] = qh ? r1 : d1;
      P.u[2] = qh ? d0 : r0;  P.u[3] = qh ? d1 : r1;

      lacc = __builtin_amdgcn_mfma_f32_32x32x16_bf16(ones.v, P.v, lacc, 0, 0, 0);
#pragma unroll
      for (int m = 0; m < 4; ++m) {
        bf16x8 vf = *(const bf16x8*)(Vs + (m * 32 + l31) * 64 + (((s * 2 + q5) ^ l7) * 8));
        acc[m] = __builtin_amdgcn_mfma_f32_32x32x16_bf16(vf, P.v, acc[m], 0, 0, 0);
      }
    }
  }

  // denominator: colsum + sink; all regs of lacc are identical
  float denom = lacc[0] + __builtin_amdgcn_exp2f(sinks[h] * 1.4426950f);
  float rinv = 1.0f / denom;

  // O^T -> LDS (swizzled) -> coalesced global store
  __syncthreads();
#pragma unroll
  for (int m = 0; m < 4; ++m) {
#pragma unroll
    for (int r = 0; r < 16; ++r) {
      int d = m * 32 + ((r >> 2) << 3) + q5 * 4 + (r & 3);
      int ql = w * 32 + l31;
      lds[ql * 128 + (((d >> 3) ^ l7) << 3) + (d & 7)] = f2bf(acc[m][r] * rinv);
    }
  }
  __syncthreads();
  const int qrow = t >> 1;
  const int half = (t & 1) * 8;
  short* ob = O + (size_t)(q0 + qrow) * 4096 + h * 128;
#pragma unroll
  for (int cc = 0; cc < 8; ++cc) {
    int chunk = half + cc;
    bf16x8 v = *(const bf16x8*)&lds[qrow * 128 + ((chunk ^ (qrow & 7)) << 3)];
    *(bf16x8*)(ob + chunk * 8) = v;
  }
}

// ---------------- host ----------------
extern "C" void kernel_launch(void* const* d_in, const int* in_sizes, int n_in,
                              void* d_out, int out_size, void* d_ws, size_t ws_size,
                              hipStream_t stream) {
  const float* hs    = (const float*)d_in[0];
  const float* cosb  = (const float*)d_in[1];
  const float* sinb  = (const float*)d_in[2];
  const float* Wq    = (const float*)d_in[4];
  const float* Wk    = (const float*)d_in[5];
  const float* Wv    = (const float*)d_in[6];
  const float* Wo    = (const float*)d_in[7];
  const float* sinks = (const float*)d_in[8];
  float* out = (float*)d_out;

  char* ws = (char*)d_ws;
  short* Xb    = (short*)ws;                    // 16.78 MB  [2048][4096]
  short* Wqkvt = (short*)(ws + 16777216);       // 50.33 MB  [6144][4096]
  short* Qb    = (short*)(ws + 67108864);       // 16.78 MB  [2048][4096]
  short* Kb    = (short*)(ws + 83886080);       //  4.19 MB  [2048][1024]
  short* Vtb   = (short*)(ws + 88080384);       //  4.19 MB  [1024][2048]
  short* Ab    = Xb;                            // alias: X dead after qkv GEMM
  short* Wot   = Wqkvt;                         // alias: Q-region dead after qkv GEMM

  cvt_f32_bf16<<<8192, 256, 0, stream>>>(hs, Xb, 2097152);
  transpose_to_bf16<<<dim3(128, 128), 256, 0, stream>>>(Wq, Wqkvt, 4096, 4096);
  transpose_to_bf16<<<dim3(32, 128), 256, 0, stream>>>(Wk, Wqkvt + (size_t)4096 * 4096, 4096, 1024);
  transpose_to_bf16<<<dim3(32, 128), 256, 0, stream>>>(Wv, Wqkvt + (size_t)5120 * 4096, 4096, 1024);

  gemm_qkv<<<dim3(48, 16), 256, 0, stream>>>(Xb, Wqkvt, Qb, Kb, Vtb, cosb, sinb);

  transpose_to_bf16<<<dim3(128, 128), 256, 0, stream>>>(Wo, Wot, 4096, 4096);

  attn_kernel<<<dim3(32, 16), 256, 0, stream>>>(Qb, Kb, Vtb, sinks, Ab);

  gemm_out<<<dim3(32, 16), 256, 0, stream>>>(Ab, Wot, out);
}

// Round 3
// 510.568 us; speedup vs baseline: 1.6899x; 1.1345x over previous
//
#include <hip/hip_runtime.h>
#include <hip/hip_bf16.h>
#include <cstdint>
#include <cstddef>

#define S_LEN 2048
#define NHEADS 32
#define NKVH   8
#define HDIM   128

using bf16x8 = __attribute__((ext_vector_type(8))) short;
using f32x4  = __attribute__((ext_vector_type(4))) float;
using f32x16 = __attribute__((ext_vector_type(16))) float;

__device__ __forceinline__ short f2bf(float f) {
  union { float f; unsigned u; } a; a.f = f;
  unsigned u = a.u;
  unsigned r = u + 0x7fffu + ((u >> 16) & 1u);   // RNE
  return (short)(r >> 16);
}
__device__ __forceinline__ unsigned pack_bf2(float lo, float hi) {
  union { float f; unsigned u; } a, b; a.f = lo; b.f = hi;
  return __builtin_amdgcn_perm(b.u, a.u, 0x07060302);
}

// async 16B global -> LDS (wave-uniform base + lane*16 on HW)
__device__ __forceinline__ void gld16(const void* g, void* l) {
  __builtin_amdgcn_global_load_lds((__attribute__((address_space(1))) void*)(void*)g,
                                   (__attribute__((address_space(3))) void*)l, 16, 0, 0);
}

// ---------------- fp32 -> bf16 elementwise (x4 vectorized) ----------------
__global__ void cvt_f32_bf16(const float* __restrict__ x, short* __restrict__ y, int n4) {
  int i = blockIdx.x * blockDim.x + threadIdx.x;
  if (i >= n4) return;
  float4 v = reinterpret_cast<const float4*>(x)[i];
  short4 o;
  o.x = f2bf(v.x); o.y = f2bf(v.y); o.z = f2bf(v.z); o.w = f2bf(v.w);
  reinterpret_cast<short4*>(y)[i] = o;
}

// ------------- transpose + convert: W[K][N] fp32 -> Wt[N][K] bf16 -------------
__global__ void transpose_to_bf16(const float* __restrict__ W, short* __restrict__ Wt,
                                  int K, int N) {
  __shared__ float tile[32][33];
  int bn = blockIdx.x * 32;
  int bk = blockIdx.y * 32;
  int tx = threadIdx.x & 31;
  int ty = (threadIdx.x >> 5) * 4;
#pragma unroll
  for (int i = 0; i < 4; ++i)
    tile[ty + i][tx] = W[(size_t)(bk + ty + i) * N + bn + tx];
  __syncthreads();
#pragma unroll
  for (int i = 0; i < 4; ++i)
    Wt[(size_t)(bn + ty + i) * K + bk + tx] = f2bf(tile[tx][ty + i]);
}

// ---------------- fused QKV GEMM + RoPE epilogue (double-buffered) ----------------
// A: X [2048][4096] bf16. B: Wqkvt [6144][4096] bf16. Outputs: Qb roped,
// Kb roped, Vtb transposed (via LDS transpose, coalesced stores).
__global__ __launch_bounds__(256)
void gemm_qkv(const short* __restrict__ A, const short* __restrict__ B,
              short* __restrict__ Qb, short* __restrict__ Kb, short* __restrict__ Vtb,
              const float* __restrict__ cosb, const float* __restrict__ sinb) {
  const int K = 4096;
  __shared__ short smem[16896];   // 33 KB: dbuf staging 2x16KB; epilogue 128x132
  const int bn = blockIdx.x * 128;
  const int bm = blockIdx.y * 128;
  const int t = threadIdx.x;
  const int lane = t & 63;
  const int wave = t >> 6;
  const int wm = (wave >> 1) * 64;
  const int wn = (wave & 1) * 64;
  const int lr = lane & 15;
  const int lk = (lane >> 4) * 8;

  f32x4 acc[4][4] = {};

  const int arow = t >> 2;
  const int acol = (t & 3) * 8;
  const size_t ab0 = (size_t)(bm + arow) * K + acol;
  const size_t ab1 = (size_t)(bm + 64 + arow) * K + acol;
  const size_t bb0 = (size_t)(bn + arow) * K + acol;
  const size_t bb1 = (size_t)(bn + 64 + arow) * K + acol;

  auto stage = [&](int k0, int b) {
    char* base = (char*)smem + b * 16384 + t * 16;
    gld16(A + ab0 + k0, base);
    gld16(A + ab1 + k0, base + 4096);
    gld16(B + bb0 + k0, base + 8192);
    gld16(B + bb1 + k0, base + 12288);
  };

  stage(0, 0);
  for (int it = 0; it < 128; ++it) {
    __syncthreads();                         // staging of buf (it&1) complete
    if (it + 1 < 128) stage((it + 1) * 32, (it + 1) & 1);   // hidden under compute
    const short* Asb = smem + (it & 1) * 8192;
    const short* Bsb = Asb + 4096;
    bf16x8 af[4], bfr[4];
#pragma unroll
    for (int i = 0; i < 4; ++i)
      af[i] = *(const bf16x8*)&Asb[(wm + i * 16 + lr) * 32 + lk];
#pragma unroll
    for (int j = 0; j < 4; ++j)
      bfr[j] = *(const bf16x8*)&Bsb[(wn + j * 16 + lr) * 32 + lk];
#pragma unroll
    for (int i = 0; i < 4; ++i)
#pragma unroll
      for (int j = 0; j < 4; ++j)
        acc[i][j] = __builtin_amdgcn_mfma_f32_16x16x32_bf16(af[i], bfr[j], acc[i][j], 0, 0, 0);
  }

  const int cr = (lane >> 4) << 2;
  const int cc = lane & 15;
  const int region = (bn >= 5120) ? 2 : (bn >= 4096 ? 1 : 0);

  if (region < 2) {
    // RoPE on cols <64 of each head-block (held by wn==0 waves)
    if (wn == 0) {
#pragma unroll
      for (int i = 0; i < 4; ++i) {
#pragma unroll
        for (int r = 0; r < 4; ++r) {
          int srow = bm + wm + i * 16 + cr + r;
#pragma unroll
          for (int j = 0; j < 2; ++j) {
            int c = j * 16 + cc;
            float cv = cosb[srow * 64 + c];
            float sv = sinb[srow * 64 + c];
            float x1 = acc[i][j][r], x2 = acc[i][j + 2][r];
            acc[i][j][r]     = x1 * cv - x2 * sv;
            acc[i][j + 2][r] = x2 * cv + x1 * sv;
          }
        }
      }
    }
#pragma unroll
    for (int i = 0; i < 4; ++i)
#pragma unroll
      for (int j = 0; j < 4; ++j) {
        int row = bm + wm + i * 16 + cr;
        int col = bn + wn + j * 16 + cc;
#pragma unroll
        for (int r = 0; r < 4; ++r) {
          short v = f2bf(acc[i][j][r]);
          if (region == 0) Qb[(size_t)(row + r) * 4096 + col] = v;
          else             Kb[(size_t)(row + r) * 1024 + (col - 4096)] = v;
        }
      }
  } else {
    // V: transpose through LDS (ld=132 breaks bank conflicts), coalesced stores
    __syncthreads();
#pragma unroll
    for (int i = 0; i < 4; ++i)
#pragma unroll
      for (int j = 0; j < 4; ++j) {
        int lc = wn + j * 16 + cc;
        int lrow = wm + i * 16 + cr;
#pragma unroll
        for (int r = 0; r < 4; ++r)
          smem[lc * 132 + lrow + r] = f2bf(acc[i][j][r]);
      }
    __syncthreads();
    const int rowl = t >> 1;
    const int off = (t & 1) * 64;
    short* dst = Vtb + (size_t)(bn - 5120 + rowl) * 2048 + bm + off;
#pragma unroll
    for (int c = 0; c < 8; ++c)
      *(bf16x8*)(dst + c * 8) = *(const bf16x8*)&smem[rowl * 132 + off + c * 8];
  }
}

// ---------------- output GEMM (double-buffered): out fp32 = A * Bt^T ----------------
__global__ __launch_bounds__(256)
void gemm_out(const short* __restrict__ A, const short* __restrict__ B,
              float* __restrict__ C) {
  const int K = 4096, N = 4096;
  __shared__ short smem[16384];   // 32 KB double buffer
  const int bn = blockIdx.x * 128;
  const int bm = blockIdx.y * 128;
  const int t = threadIdx.x;
  const int lane = t & 63;
  const int wave = t >> 6;
  const int wm = (wave >> 1) * 64;
  const int wn = (wave & 1) * 64;
  const int lr = lane & 15;
  const int lk = (lane >> 4) * 8;

  f32x4 acc[4][4] = {};

  const int arow = t >> 2;
  const int acol = (t & 3) * 8;
  const size_t ab0 = (size_t)(bm + arow) * K + acol;
  const size_t ab1 = (size_t)(bm + 64 + arow) * K + acol;
  const size_t bb0 = (size_t)(bn + arow) * K + acol;
  const size_t bb1 = (size_t)(bn + 64 + arow) * K + acol;

  auto stage = [&](int k0, int b) {
    char* base = (char*)smem + b * 16384 + t * 16;
    gld16(A + ab0 + k0, base);
    gld16(A + ab1 + k0, base + 4096);
    gld16(B + bb0 + k0, base + 8192);
    gld16(B + bb1 + k0, base + 12288);
  };

  stage(0, 0);
  for (int it = 0; it < 128; ++it) {
    __syncthreads();
    if (it + 1 < 128) stage((it + 1) * 32, (it + 1) & 1);
    const short* Asb = smem + (it & 1) * 8192;
    const short* Bsb = Asb + 4096;
    bf16x8 af[4], bfr[4];
#pragma unroll
    for (int i = 0; i < 4; ++i)
      af[i] = *(const bf16x8*)&Asb[(wm + i * 16 + lr) * 32 + lk];
#pragma unroll
    for (int j = 0; j < 4; ++j)
      bfr[j] = *(const bf16x8*)&Bsb[(wn + j * 16 + lr) * 32 + lk];
#pragma unroll
    for (int i = 0; i < 4; ++i)
#pragma unroll
      for (int j = 0; j < 4; ++j)
        acc[i][j] = __builtin_amdgcn_mfma_f32_16x16x32_bf16(af[i], bfr[j], acc[i][j], 0, 0, 0);
  }

  const int cr = (lane >> 4) << 2;
  const int cc = lane & 15;
#pragma unroll
  for (int i = 0; i < 4; ++i)
#pragma unroll
    for (int j = 0; j < 4; ++j) {
      int row = bm + wm + i * 16 + cr;
      int col = bn + wn + j * 16 + cc;
#pragma unroll
      for (int r = 0; r < 4; ++r)
        C[(size_t)(row + r) * N + col] = acc[i][j][r];
    }
}

// ---------------- flash attention, S^T form, max-free softmax ----------------
__global__ __launch_bounds__(256, 2)
void attn_kernel(const short* __restrict__ Q, const short* __restrict__ Kg,
                 const short* __restrict__ Vg, const float* __restrict__ sinks,
                 short* __restrict__ O) {
  __shared__ short lds[32768];   // 64 KB: buf0 [Ks 8192 | Vs 8192], buf1 same
  const int h = blockIdx.x;
  const int qt = 15 - blockIdx.y;          // heavy tiles first
  const int q0 = qt * 128;
  const int kvh = h >> 2;
  const int t = threadIdx.x;
  const int lane = t & 63;
  const int w = t >> 6;
  const int l31 = lane & 31;
  const int l7 = lane & 7;
  const bool qh = lane >= 32;
  const int q5 = qh ? 1 : 0;
  const int nkt = 2 * qt + 2;

  const int kch = (t & 15) ^ ((t >> 4) & 7);
  const short* kgb = Kg + (size_t)(t >> 4) * 1024 + kvh * 128 + kch * 8;
  const int vch = (t & 7) ^ ((t >> 3) & 7);
  const short* vgb = Vg + (size_t)(kvh * 128 + (t >> 3)) * 2048 + vch * 8;

  auto stage = [&](int kt, int b) {
    short* kl = lds + b * 16384 + t * 8;
    short* vl = lds + b * 16384 + 8192 + t * 8;
    const short* kg = kgb + (size_t)kt * 64 * 1024;
    const short* vg = vgb + kt * 64;
#pragma unroll
    for (int c = 0; c < 4; ++c) {
      gld16(kg + (size_t)c * 16 * 1024, kl + c * 2048);
      gld16(vg + (size_t)c * 32 * 2048, vl + c * 2048);
    }
  };

  const short* qp = Q + (size_t)(q0 + w * 32 + l31) * 4096 + h * 128 + q5 * 8;
  bf16x8 qf[8];
#pragma unroll
  for (int st = 0; st < 8; ++st) qf[st] = *(const bf16x8*)(qp + st * 16);

  union { short s[8]; bf16x8 v; } ones;
#pragma unroll
  for (int i = 0; i < 8; ++i) ones.s[i] = (short)0x3F80;

  f32x16 acc[4] = {};
  f32x16 lacc = {};

  stage(0, 0);
  const int qg = q0 + w * 32 + l31;
  const float ce = 0.12751743f;   // (1/sqrt(128)) * log2(e)

  for (int kt = 0; kt < nkt; ++kt) {
    const int b = kt & 1;
    __syncthreads();
    if (kt + 1 < nkt) stage(kt + 1, b ^ 1);
    const short* Ks = lds + b * 16384;
    const short* Vs = Ks + 8192;

    f32x16 sa0 = {}, sa1 = {};
#pragma unroll
    for (int st = 0; st < 8; ++st) {
      const int cp = ((st * 2 + q5) ^ l7) * 8;
      bf16x8 k0 = *(const bf16x8*)(Ks + (l31) * 128 + cp);
      bf16x8 k1 = *(const bf16x8*)(Ks + (32 + l31) * 128 + cp);
      sa0 = __builtin_amdgcn_mfma_f32_32x32x16_bf16(k0, qf[st], sa0, 0, 0, 0);
      sa1 = __builtin_amdgcn_mfma_f32_32x32x16_bf16(k1, qf[st], sa1, 0, 0, 0);
    }

    if (kt >= 2 * qt) {
      const int kb0 = kt * 64 + q5 * 4;
#pragma unroll
      for (int r = 0; r < 16; ++r) {
        int kg0 = kb0 + ((r >> 2) << 3) + (r & 3);
        float s0 = (kg0 <= qg) ? sa0[r] * ce : -INFINITY;
        float s1 = (kg0 + 32 <= qg) ? sa1[r] * ce : -INFINITY;
        sa0[r] = __builtin_amdgcn_exp2f(s0);
        sa1[r] = __builtin_amdgcn_exp2f(s1);
      }
    } else {
#pragma unroll
      for (int r = 0; r < 16; ++r) {
        sa0[r] = __builtin_amdgcn_exp2f(sa0[r] * ce);
        sa1[r] = __builtin_amdgcn_exp2f(sa1[r] * ce);
      }
    }

#pragma unroll
    for (int s = 0; s < 4; ++s) {
      const f32x16& S = (s & 2) ? sa1 : sa0;
      float a0, a1, a2, a3, b0, b1, b2, b3;
      if (s & 1) {
        a0 = qh ? S[12] : S[8];  a1 = qh ? S[13] : S[9];
        a2 = qh ? S[14] : S[10]; a3 = qh ? S[15] : S[11];
        b0 = qh ? S[8]  : S[12]; b1 = qh ? S[9]  : S[13];
        b2 = qh ? S[10] : S[14]; b3 = qh ? S[11] : S[15];
      } else {
        a0 = qh ? S[4] : S[0]; a1 = qh ? S[5] : S[1];
        a2 = qh ? S[6] : S[2]; a3 = qh ? S[7] : S[3];
        b0 = qh ? S[0] : S[4]; b1 = qh ? S[1] : S[5];
        b2 = qh ? S[2] : S[6]; b3 = qh ? S[3] : S[7];
      }
      unsigned d0 = pack_bf2(a0, a1), d1 = pack_bf2(a2, a3);
      unsigned e0 = pack_bf2(b0, b1), e1 = pack_bf2(b2, b3);
      unsigned r0 = (unsigned)__shfl_xor((int)e0, 32, 64);
      unsigned r1 = (unsigned)__shfl_xor((int)e1, 32, 64);
      union { unsigned u[4]; bf16x8 v; } P;
      P.u[0] = qh ? r0 : d0;  P.u[1] = qh ? r1 : d1;
      P.u[2] = qh ? d0 : r0;  P.u[3] = qh ? d1 : r1;

      lacc = __builtin_amdgcn_mfma_f32_32x32x16_bf16(ones.v, P.v, lacc, 0, 0, 0);
#pragma unroll
      for (int m = 0; m < 4; ++m) {
        bf16x8 vf = *(const bf16x8*)(Vs + (m * 32 + l31) * 64 + (((s * 2 + q5) ^ l7) * 8));
        acc[m] = __builtin_amdgcn_mfma_f32_32x32x16_bf16(vf, P.v, acc[m], 0, 0, 0);
      }
    }
  }

  float denom = lacc[0] + __builtin_amdgcn_exp2f(sinks[h] * 1.4426950f);
  float rinv = 1.0f / denom;

  __syncthreads();
#pragma unroll
  for (int m = 0; m < 4; ++m) {
#pragma unroll
    for (int r = 0; r < 16; ++r) {
      int d = m * 32 + ((r >> 2) << 3) + q5 * 4 + (r & 3);
      int ql = w * 32 + l31;
      lds[ql * 128 + (((d >> 3) ^ l7) << 3) + (d & 7)] = f2bf(acc[m][r] * rinv);
    }
  }
  __syncthreads();
  const int qrow = t >> 1;
  const int half = (t & 1) * 8;
  short* ob = O + (size_t)(q0 + qrow) * 4096 + h * 128;
#pragma unroll
  for (int cc = 0; cc < 8; ++cc) {
    int chunk = half + cc;
    bf16x8 v = *(const bf16x8*)&lds[qrow * 128 + ((chunk ^ (qrow & 7)) << 3)];
    *(bf16x8*)(ob + chunk * 8) = v;
  }
}

// ---------------- host ----------------
extern "C" void kernel_launch(void* const* d_in, const int* in_sizes, int n_in,
                              void* d_out, int out_size, void* d_ws, size_t ws_size,
                              hipStream_t stream) {
  const float* hs    = (const float*)d_in[0];
  const float* cosb  = (const float*)d_in[1];
  const float* sinb  = (const float*)d_in[2];
  const float* Wq    = (const float*)d_in[4];
  const float* Wk    = (const float*)d_in[5];
  const float* Wv    = (const float*)d_in[6];
  const float* Wo    = (const float*)d_in[7];
  const float* sinks = (const float*)d_in[8];
  float* out = (float*)d_out;

  char* ws = (char*)d_ws;
  short* Xb    = (short*)ws;                    // 16.78 MB  [2048][4096]
  short* Wqkvt = (short*)(ws + 16777216);       // 50.33 MB  [6144][4096]
  short* Qb    = (short*)(ws + 67108864);       // 16.78 MB  [2048][4096]
  short* Kb    = (short*)(ws + 83886080);       //  4.19 MB  [2048][1024]
  short* Vtb   = (short*)(ws + 88080384);       //  4.19 MB  [1024][2048]
  short* Ab    = Xb;                            // alias: X dead after qkv GEMM
  short* Wot   = Wqkvt;                         // alias: dead after qkv GEMM

  cvt_f32_bf16<<<8192, 256, 0, stream>>>(hs, Xb, 2097152);
  transpose_to_bf16<<<dim3(128, 128), 256, 0, stream>>>(Wq, Wqkvt, 4096, 4096);
  transpose_to_bf16<<<dim3(32, 128), 256, 0, stream>>>(Wk, Wqkvt + (size_t)4096 * 4096, 4096, 1024);
  transpose_to_bf16<<<dim3(32, 128), 256, 0, stream>>>(Wv, Wqkvt + (size_t)5120 * 4096, 4096, 1024);

  gemm_qkv<<<dim3(48, 16), 256, 0, stream>>>(Xb, Wqkvt, Qb, Kb, Vtb, cosb, sinb);

  transpose_to_bf16<<<dim3(128, 128), 256, 0, stream>>>(Wo, Wot, 4096, 4096);

  attn_kernel<<<dim3(32, 16), 256, 0, stream>>>(Qb, Kb, Vtb, sinks, Ab);

  gemm_out<<<dim3(32, 16), 256, 0, stream>>>(Ab, Wot, out);
}

// Round 4
// 490.647 us; speedup vs baseline: 1.7585x; 1.0406x over previous
//
#include <hip/hip_runtime.h>
#include <hip/hip_bf16.h>
#include <cstdint>
#include <cstddef>

#define S_LEN 2048
#define NHEADS 32
#define NKVH   8
#define HDIM   128

using bf16x8 = __attribute__((ext_vector_type(8))) short;
using f32x4  = __attribute__((ext_vector_type(4))) float;
using f32x16 = __attribute__((ext_vector_type(16))) float;

__device__ __forceinline__ short f2bf(float f) {
  union { float f; unsigned u; } a; a.f = f;
  unsigned u = a.u;
  unsigned r = u + 0x7fffu + ((u >> 16) & 1u);   // RNE
  return (short)(r >> 16);
}
__device__ __forceinline__ unsigned pack_bf2(float lo, float hi) {
  union { float f; unsigned u; } a, b; a.f = lo; b.f = hi;
  return __builtin_amdgcn_perm(b.u, a.u, 0x07060302);
}

// async 16B global -> LDS (wave-uniform base + lane*16 on HW)
__device__ __forceinline__ void gld16(const void* g, void* l) {
  __builtin_amdgcn_global_load_lds((__attribute__((address_space(1))) void*)(void*)g,
                                   (__attribute__((address_space(3))) void*)l, 16, 0, 0);
}

// ---------------- fp32 -> bf16 elementwise (x4 vectorized) ----------------
__global__ void cvt_f32_bf16(const float* __restrict__ x, short* __restrict__ y, int n4) {
  int i = blockIdx.x * blockDim.x + threadIdx.x;
  if (i >= n4) return;
  float4 v = reinterpret_cast<const float4*>(x)[i];
  short4 o;
  o.x = f2bf(v.x); o.y = f2bf(v.y); o.z = f2bf(v.z); o.w = f2bf(v.w);
  reinterpret_cast<short4*>(y)[i] = o;
}

// ------------- transpose + convert: W[K][N] fp32 -> Wt[N][K] bf16 -------------
// 32x32 tile, 256 threads: float4 loads, short4 stores, <=2-way LDS conflicts.
__global__ __launch_bounds__(256)
void transpose_to_bf16(const float* __restrict__ W, short* __restrict__ Wt,
                       int K, int N) {
  __shared__ float tile[32 * 33];
  const int bn = blockIdx.x * 32, bk = blockIdx.y * 32;
  const int t = threadIdx.x;
  const int c4 = t & 7, kr = t >> 3;
  float4 v = *(const float4*)&W[(size_t)(bk + kr) * N + bn + c4 * 4];
  tile[kr * 33 + c4 * 4 + 0] = v.x;
  tile[kr * 33 + c4 * 4 + 1] = v.y;
  tile[kr * 33 + c4 * 4 + 2] = v.z;
  tile[kr * 33 + c4 * 4 + 3] = v.w;
  __syncthreads();
  const int k4 = t & 7, nr = t >> 3;
  short4 o;
  o.x = f2bf(tile[(k4 * 4 + 0) * 33 + nr]);
  o.y = f2bf(tile[(k4 * 4 + 1) * 33 + nr]);
  o.z = f2bf(tile[(k4 * 4 + 2) * 33 + nr]);
  o.w = f2bf(tile[(k4 * 4 + 3) * 33 + nr]);
  *(short4*)&Wt[(size_t)(bn + nr) * K + bk + k4 * 4] = o;
}

// ---------------- fused QKV GEMM + RoPE epilogue (double-buffered) ----------------
__global__ __launch_bounds__(256)
void gemm_qkv(const short* __restrict__ A, const short* __restrict__ B,
              short* __restrict__ Qb, short* __restrict__ Kb, short* __restrict__ Vtb,
              const float* __restrict__ cosb, const float* __restrict__ sinb) {
  const int K = 4096;
  __shared__ short smem[16896];   // 33 KB: dbuf staging 2x16KB; epilogue 128x132
  const int bn = blockIdx.x * 128;
  const int bm = blockIdx.y * 128;
  const int t = threadIdx.x;
  const int lane = t & 63;
  const int wave = t >> 6;
  const int wm = (wave >> 1) * 64;
  const int wn = (wave & 1) * 64;
  const int lr = lane & 15;
  const int lk = (lane >> 4) * 8;

  f32x4 acc[4][4] = {};

  const int arow = t >> 2;
  const int acol = (t & 3) * 8;
  const size_t ab0 = (size_t)(bm + arow) * K + acol;
  const size_t ab1 = (size_t)(bm + 64 + arow) * K + acol;
  const size_t bb0 = (size_t)(bn + arow) * K + acol;
  const size_t bb1 = (size_t)(bn + 64 + arow) * K + acol;

  auto stage = [&](int k0, int b) {
    char* base = (char*)smem + b * 16384 + t * 16;
    gld16(A + ab0 + k0, base);
    gld16(A + ab1 + k0, base + 4096);
    gld16(B + bb0 + k0, base + 8192);
    gld16(B + bb1 + k0, base + 12288);
  };

  stage(0, 0);
  for (int it = 0; it < 128; ++it) {
    __syncthreads();
    if (it + 1 < 128) stage((it + 1) * 32, (it + 1) & 1);
    const short* Asb = smem + (it & 1) * 8192;
    const short* Bsb = Asb + 4096;
    bf16x8 af[4], bfr[4];
#pragma unroll
    for (int i = 0; i < 4; ++i)
      af[i] = *(const bf16x8*)&Asb[(wm + i * 16 + lr) * 32 + lk];
#pragma unroll
    for (int j = 0; j < 4; ++j)
      bfr[j] = *(const bf16x8*)&Bsb[(wn + j * 16 + lr) * 32 + lk];
#pragma unroll
    for (int i = 0; i < 4; ++i)
#pragma unroll
      for (int j = 0; j < 4; ++j)
        acc[i][j] = __builtin_amdgcn_mfma_f32_16x16x32_bf16(af[i], bfr[j], acc[i][j], 0, 0, 0);
  }

  const int cr = (lane >> 4) << 2;
  const int cc = lane & 15;
  const int region = (bn >= 5120) ? 2 : (bn >= 4096 ? 1 : 0);

  if (region < 2) {
    if (wn == 0) {
#pragma unroll
      for (int i = 0; i < 4; ++i) {
#pragma unroll
        for (int r = 0; r < 4; ++r) {
          int srow = bm + wm + i * 16 + cr + r;
#pragma unroll
          for (int j = 0; j < 2; ++j) {
            int c = j * 16 + cc;
            float cv = cosb[srow * 64 + c];
            float sv = sinb[srow * 64 + c];
            float x1 = acc[i][j][r], x2 = acc[i][j + 2][r];
            acc[i][j][r]     = x1 * cv - x2 * sv;
            acc[i][j + 2][r] = x2 * cv + x1 * sv;
          }
        }
      }
    }
#pragma unroll
    for (int i = 0; i < 4; ++i)
#pragma unroll
      for (int j = 0; j < 4; ++j) {
        int row = bm + wm + i * 16 + cr;
        int col = bn + wn + j * 16 + cc;
#pragma unroll
        for (int r = 0; r < 4; ++r) {
          short v = f2bf(acc[i][j][r]);
          if (region == 0) Qb[(size_t)(row + r) * 4096 + col] = v;
          else             Kb[(size_t)(row + r) * 1024 + (col - 4096)] = v;
        }
      }
  } else {
    // V: transpose through LDS (ld=132), coalesced 16B stores
    __syncthreads();
#pragma unroll
    for (int i = 0; i < 4; ++i)
#pragma unroll
      for (int j = 0; j < 4; ++j) {
        int lc = wn + j * 16 + cc;
        int lrow = wm + i * 16 + cr;
#pragma unroll
        for (int r = 0; r < 4; ++r)
          smem[lc * 132 + lrow + r] = f2bf(acc[i][j][r]);
      }
    __syncthreads();
    const int rowl = t >> 1;
    const int off = (t & 1) * 64;
    short* dst = Vtb + (size_t)(bn - 5120 + rowl) * 2048 + bm + off;
#pragma unroll
    for (int c = 0; c < 8; ++c)
      *(bf16x8*)(dst + c * 8) = *(const bf16x8*)&smem[rowl * 132 + off + c * 8];
  }
}

// ---------------- output GEMM: BK=64 double-buffered, swizzled LDS ----------------
__global__ __launch_bounds__(256, 2)
void gemm_out(const short* __restrict__ A, const short* __restrict__ B,
              float* __restrict__ C) {
  const int K = 4096, N = 4096;
  __shared__ short smem[32768];          // 64 KB: 2 x (A 16KB | B 16KB)
  const int bn = blockIdx.x * 128;
  const int bm = blockIdx.y * 128;
  const int t = threadIdx.x;
  const int lane = t & 63;
  const int wave = t >> 6;
  const int wm = (wave >> 1) * 64;
  const int wn = (wave & 1) * 64;
  const int lr = lane & 15;
  const int lk3 = lane >> 4;             // k-chunk 0..3

  f32x4 acc[4][4] = {};

  const int srow = t >> 3;               // 0..31
  const int sch = (t & 7) ^ ((srow & 1) << 2);   // source-permuted chunk
  const size_t ab = (size_t)(bm + srow) * K + sch * 8;
  const size_t bb = (size_t)(bn + srow) * K + sch * 8;

  auto stage = [&](int k0, int b) {
    short* dst = smem + b * 16384 + t * 8;
#pragma unroll
    for (int p = 0; p < 4; ++p) {
      gld16(A + ab + k0 + (size_t)(p * 32) * K, dst + p * 2048);
      gld16(B + bb + k0 + (size_t)(p * 32) * K, dst + 8192 + p * 2048);
    }
  };

  stage(0, 0);
  for (int it = 0; it < 64; ++it) {
    __syncthreads();
    if (it + 1 < 64) stage((it + 1) * 64, (it + 1) & 1);
    const short* Asb = smem + (it & 1) * 16384;
    const short* Bsb = Asb + 8192;
#pragma unroll
    for (int h = 0; h < 2; ++h) {
      bf16x8 af[4], bfr[4];
#pragma unroll
      for (int i = 0; i < 4; ++i) {
        int row = wm + i * 16 + lr;
        af[i] = *(const bf16x8*)&Asb[row * 64 + (((h * 4 + lk3) ^ ((row & 1) << 2)) * 8)];
      }
#pragma unroll
      for (int j = 0; j < 4; ++j) {
        int row = wn + j * 16 + lr;
        bfr[j] = *(const bf16x8*)&Bsb[row * 64 + (((h * 4 + lk3) ^ ((row & 1) << 2)) * 8)];
      }
#pragma unroll
      for (int i = 0; i < 4; ++i)
#pragma unroll
        for (int j = 0; j < 4; ++j)
          acc[i][j] = __builtin_amdgcn_mfma_f32_16x16x32_bf16(af[i], bfr[j], acc[i][j], 0, 0, 0);
    }
  }

  const int cr = (lane >> 4) << 2;
  const int cc = lane & 15;
#pragma unroll
  for (int i = 0; i < 4; ++i)
#pragma unroll
    for (int j = 0; j < 4; ++j) {
      int row = bm + wm + i * 16 + cr;
      int col = bn + wn + j * 16 + cc;
#pragma unroll
      for (int r = 0; r < 4; ++r)
        C[(size_t)(row + r) * N + col] = acc[i][j][r];
    }
}

// ---------------- flash attention, S^T form, max-free softmax ----------------
__global__ __launch_bounds__(256, 2)
void attn_kernel(const short* __restrict__ Q, const short* __restrict__ Kg,
                 const short* __restrict__ Vg, const float* __restrict__ sinks,
                 short* __restrict__ O) {
  __shared__ short lds[32768];   // 64 KB: buf0 [Ks 8192 | Vs 8192], buf1 same
  const int h = blockIdx.x;
  const int qt = 15 - blockIdx.y;
  const int q0 = qt * 128;
  const int kvh = h >> 2;
  const int t = threadIdx.x;
  const int lane = t & 63;
  const int w = t >> 6;
  const int l31 = lane & 31;
  const int l7 = lane & 7;
  const bool qh = lane >= 32;
  const int q5 = qh ? 1 : 0;
  const int nkt = 2 * qt + 2;

  const int kch = (t & 15) ^ ((t >> 4) & 7);
  const short* kgb = Kg + (size_t)(t >> 4) * 1024 + kvh * 128 + kch * 8;
  const int vch = (t & 7) ^ ((t >> 3) & 7);
  const short* vgb = Vg + (size_t)(kvh * 128 + (t >> 3)) * 2048 + vch * 8;

  auto stage = [&](int kt, int b) {
    short* kl = lds + b * 16384 + t * 8;
    short* vl = lds + b * 16384 + 8192 + t * 8;
    const short* kg = kgb + (size_t)kt * 64 * 1024;
    const short* vg = vgb + kt * 64;
#pragma unroll
    for (int c = 0; c < 4; ++c) {
      gld16(kg + (size_t)c * 16 * 1024, kl + c * 2048);
      gld16(vg + (size_t)c * 32 * 2048, vl + c * 2048);
    }
  };

  const short* qp = Q + (size_t)(q0 + w * 32 + l31) * 4096 + h * 128 + q5 * 8;
  bf16x8 qf[8];
#pragma unroll
  for (int st = 0; st < 8; ++st) qf[st] = *(const bf16x8*)(qp + st * 16);

  union { short s[8]; bf16x8 v; } ones;
#pragma unroll
  for (int i = 0; i < 8; ++i) ones.s[i] = (short)0x3F80;

  f32x16 acc[4] = {};
  f32x16 lacc = {};

  stage(0, 0);
  const int qg = q0 + w * 32 + l31;
  const float ce = 0.12751743f;   // (1/sqrt(128)) * log2(e)

  for (int kt = 0; kt < nkt; ++kt) {
    const int b = kt & 1;
    __syncthreads();
    if (kt + 1 < nkt) stage(kt + 1, b ^ 1);
    const short* Ks = lds + b * 16384;
    const short* Vs = Ks + 8192;

    f32x16 sa0 = {}, sa1 = {};
#pragma unroll
    for (int st = 0; st < 8; ++st) {
      const int cp = ((st * 2 + q5) ^ l7) * 8;
      bf16x8 k0 = *(const bf16x8*)(Ks + (l31) * 128 + cp);
      bf16x8 k1 = *(const bf16x8*)(Ks + (32 + l31) * 128 + cp);
      sa0 = __builtin_amdgcn_mfma_f32_32x32x16_bf16(k0, qf[st], sa0, 0, 0, 0);
      sa1 = __builtin_amdgcn_mfma_f32_32x32x16_bf16(k1, qf[st], sa1, 0, 0, 0);
    }

    if (kt >= 2 * qt) {
      const int kb0 = kt * 64 + q5 * 4;
#pragma unroll
      for (int r = 0; r < 16; ++r) {
        int kg0 = kb0 + ((r >> 2) << 3) + (r & 3);
        float s0 = (kg0 <= qg) ? sa0[r] * ce : -INFINITY;
        float s1 = (kg0 + 32 <= qg) ? sa1[r] * ce : -INFINITY;
        sa0[r] = __builtin_amdgcn_exp2f(s0);
        sa1[r] = __builtin_amdgcn_exp2f(s1);
      }
    } else {
#pragma unroll
      for (int r = 0; r < 16; ++r) {
        sa0[r] = __builtin_amdgcn_exp2f(sa0[r] * ce);
        sa1[r] = __builtin_amdgcn_exp2f(sa1[r] * ce);
      }
    }

#pragma unroll
    for (int s = 0; s < 4; ++s) {
      const f32x16& S = (s & 2) ? sa1 : sa0;
      float a0, a1, a2, a3, b0, b1, b2, b3;
      if (s & 1) {
        a0 = qh ? S[12] : S[8];  a1 = qh ? S[13] : S[9];
        a2 = qh ? S[14] : S[10]; a3 = qh ? S[15] : S[11];
        b0 = qh ? S[8]  : S[12]; b1 = qh ? S[9]  : S[13];
        b2 = qh ? S[10] : S[14]; b3 = qh ? S[11] : S[15];
      } else {
        a0 = qh ? S[4] : S[0]; a1 = qh ? S[5] : S[1];
        a2 = qh ? S[6] : S[2]; a3 = qh ? S[7] : S[3];
        b0 = qh ? S[0] : S[4]; b1 = qh ? S[1] : S[5];
        b2 = qh ? S[2] : S[6]; b3 = qh ? S[3] : S[7];
      }
      unsigned d0 = pack_bf2(a0, a1), d1 = pack_bf2(a2, a3);
      unsigned e0 = pack_bf2(b0, b1), e1 = pack_bf2(b2, b3);
      unsigned r0 = (unsigned)__shfl_xor((int)e0, 32, 64);
      unsigned r1 = (unsigned)__shfl_xor((int)e1, 32, 64);
      union { unsigned u[4]; bf16x8 v; } P;
      P.u[0] = qh ? r0 : d0;  P.u[1] = qh ? r1 : d1;
      P.u[2] = qh ? d0 : r0;  P.u[3] = qh ? d1 : r1;

      lacc = __builtin_amdgcn_mfma_f32_32x32x16_bf16(ones.v, P.v, lacc, 0, 0, 0);
#pragma unroll
      for (int m = 0; m < 4; ++m) {
        bf16x8 vf = *(const bf16x8*)(Vs + (m * 32 + l31) * 64 + (((s * 2 + q5) ^ l7) * 8));
        acc[m] = __builtin_amdgcn_mfma_f32_32x32x16_bf16(vf, P.v, acc[m], 0, 0, 0);
      }
    }
  }

  float denom = lacc[0] + __builtin_amdgcn_exp2f(sinks[h] * 1.4426950f);
  float rinv = 1.0f / denom;

  __syncthreads();
#pragma unroll
  for (int m = 0; m < 4; ++m) {
#pragma unroll
    for (int r = 0; r < 16; ++r) {
      int d = m * 32 + ((r >> 2) << 3) + q5 * 4 + (r & 3);
      int ql = w * 32 + l31;
      lds[ql * 128 + (((d >> 3) ^ l7) << 3) + (d & 7)] = f2bf(acc[m][r] * rinv);
    }
  }
  __syncthreads();
  const int qrow = t >> 1;
  const int half = (t & 1) * 8;
  short* ob = O + (size_t)(q0 + qrow) * 4096 + h * 128;
#pragma unroll
  for (int cc = 0; cc < 8; ++cc) {
    int chunk = half + cc;
    bf16x8 v = *(const bf16x8*)&lds[qrow * 128 + ((chunk ^ (qrow & 7)) << 3)];
    *(bf16x8*)(ob + chunk * 8) = v;
  }
}

// ---------------- host ----------------
extern "C" void kernel_launch(void* const* d_in, const int* in_sizes, int n_in,
                              void* d_out, int out_size, void* d_ws, size_t ws_size,
                              hipStream_t stream) {
  const float* hs    = (const float*)d_in[0];
  const float* cosb  = (const float*)d_in[1];
  const float* sinb  = (const float*)d_in[2];
  const float* Wq    = (const float*)d_in[4];
  const float* Wk    = (const float*)d_in[5];
  const float* Wv    = (const float*)d_in[6];
  const float* Wo    = (const float*)d_in[7];
  const float* sinks = (const float*)d_in[8];
  float* out = (float*)d_out;

  char* ws = (char*)d_ws;
  short* Xb    = (short*)ws;                    // 16.78 MB  [2048][4096]
  short* Wqkvt = (short*)(ws + 16777216);       // 50.33 MB  [6144][4096]
  short* Qb    = (short*)(ws + 67108864);       // 16.78 MB  [2048][4096]
  short* Kb    = (short*)(ws + 83886080);       //  4.19 MB  [2048][1024]
  short* Vtb   = (short*)(ws + 88080384);       //  4.19 MB  [1024][2048]
  short* Ab    = Xb;                            // alias: X dead after qkv GEMM
  short* Wot   = Wqkvt;                         // alias: dead after qkv GEMM

  cvt_f32_bf16<<<8192, 256, 0, stream>>>(hs, Xb, 2097152);
  transpose_to_bf16<<<dim3(128, 128), 256, 0, stream>>>(Wq, Wqkvt, 4096, 4096);
  transpose_to_bf16<<<dim3(32, 128), 256, 0, stream>>>(Wk, Wqkvt + (size_t)4096 * 4096, 4096, 1024);
  transpose_to_bf16<<<dim3(32, 128), 256, 0, stream>>>(Wv, Wqkvt + (size_t)5120 * 4096, 4096, 1024);

  gemm_qkv<<<dim3(48, 16), 256, 0, stream>>>(Xb, Wqkvt, Qb, Kb, Vtb, cosb, sinb);

  transpose_to_bf16<<<dim3(128, 128), 256, 0, stream>>>(Wo, Wot, 4096, 4096);

  attn_kernel<<<dim3(32, 16), 256, 0, stream>>>(Qb, Kb, Vtb, sinks, Ab);

  gemm_out<<<dim3(32, 16), 256, 0, stream>>>(Ab, Wot, out);
}